// Round 14
// baseline (76.120 us; speedup 1.0000x reference)
//
#include <hip/hip_runtime.h>

// Swin-style attention: B=16, N=1024 (32x32), H=8, D=32, C=256.
// R13: softmax row-sums computed by MFMA with an all-ones B-fragment
// (ls = P . 1), replacing 16 VALU adds/iter AND the epilogue shuffle
// reductions (lsv fragment layout == O fragment layout). Depth-1 K/V
// prefetch (depth-2 rotation was pure register-move overhead, R12 null).
// Bias rides QK MFMA C-operand (R11); V fragment-subtiled (R6); j-split (R10).

using f32x4  = __attribute__((ext_vector_type(4))) float;
using bf16x8 = __attribute__((ext_vector_type(8))) short;

__device__ __forceinline__ short f2bf(float f) {
  union { float f; unsigned u; } v; v.f = f;
  return (short)((v.u + 0x7FFFu + ((v.u >> 16) & 1u)) >> 16);  // RNE
}
__device__ __forceinline__ f32x4 mfma_k32(bf16x8 a, bf16x8 b, f32x4 c) {
  return __builtin_amdgcn_mfma_f32_16x16x32_bf16(a, b, c, 0, 0, 0);
}
__device__ __forceinline__ int cvt_pk_bf16(float lo, float hi) {
  int r;
  asm("v_cvt_pk_bf16_f32 %0, %1, %2" : "=v"(r) : "v"(lo), "v"(hi));
  return r;
}
// bias fragment: C[r] = row[p - r]
__device__ __forceinline__ f32x4 ldb(const float* __restrict__ row, int p) {
  f32x4 v;
  v[0] = row[p]; v[1] = row[p - 1]; v[2] = row[p - 2]; v[3] = row[p - 3];
  return v;
}

#define CSQ 0.25500526817f  /* (1/sqrt(32)) * log2(e) */

// ------- kernel 0: weight transposes (LDS-tiled, coalesced) + bias prep -------
__global__ __launch_bounds__(256) void k_prep(const float* __restrict__ Wq,
    const float* __restrict__ Wk, const float* __restrict__ Wv,
    const float* __restrict__ Wo, short* __restrict__ WT,
    const float* __restrict__ bt, float* __restrict__ Tg) {
  int bx = blockIdx.x;
  if (bx < 64) {
    __shared__ float tile[64][65];
    int wid = bx >> 4, t = bx & 15;
    int ro0 = (t & 3) * 64, co0 = (t >> 2) * 64;
    const float* W = wid == 0 ? Wq : wid == 1 ? Wk : wid == 2 ? Wv : Wo;
    int tr = threadIdx.x >> 4, tc = threadIdx.x & 15;
    #pragma unroll
    for (int c = 0; c < 4; ++c) {
      int row = c * 16 + tr;
      float4 v = *reinterpret_cast<const float4*>(
          &W[(ro0 + row) * 256 + co0 + tc * 4]);
      tile[row][tc * 4 + 0] = v.x;
      tile[row][tc * 4 + 1] = v.y;
      tile[row][tc * 4 + 2] = v.z;
      tile[row][tc * 4 + 3] = v.w;
    }
    __syncthreads();
    #pragma unroll
    for (int c = 0; c < 4; ++c) {
      int orow = c * 16 + tr;
      short4 s;
      s.x = f2bf(tile[tc * 4 + 0][orow]);
      s.y = f2bf(tile[tc * 4 + 1][orow]);
      s.z = f2bf(tile[tc * 4 + 2][orow]);
      s.w = f2bf(tile[tc * 4 + 3][orow]);
      *reinterpret_cast<short4*>(
          &WT[wid * 65536 + (co0 + orow) * 256 + ro0 + tc * 4]) = s;
    }
  } else {
    int idx = (bx - 64) * 256 + threadIdx.x;  // 128 x 256 = 8 x 4096
    int h = idx >> 12, i = idx & 4095;
    if (i < 3969) Tg[idx] = bt[i * 8 + h] * 1.4426950408889634f;
  }
}

// ---------------- kernel 1: QKV projection, W via dbuf LDS (R9) ----------------
__global__ __launch_bounds__(256) void k_qkv(const float* __restrict__ x,
    const short* __restrict__ WT,
    short* __restrict__ Q, short* __restrict__ K, short* __restrict__ Vt) {
  __shared__ short Wlds[2][4096];  // 2 x 8KB
  char* lbase = (char*)Wlds;
  const int tid = threadIdx.x;
  const int w = tid >> 6, l = tid & 63, lr = l & 15, lg = l >> 4;
  const int m0 = blockIdx.x * 64;
  const int wi = blockIdx.y;
  const char* Wb = (const char*)(WT + wi * 65536);
  const float* xrow = x + (size_t)(m0 + w * 16 + lr) * 256;
  bf16x8 af[8];
  #pragma unroll
  for (int kc = 0; kc < 8; ++kc) {
    float4 a = *reinterpret_cast<const float4*>(xrow + kc * 32 + lg * 8);
    float4 c = *reinterpret_cast<const float4*>(xrow + kc * 32 + lg * 8 + 4);
    union { int i4[4]; bf16x8 v; } u;
    u.i4[0] = cvt_pk_bf16(a.x, a.y);
    u.i4[1] = cvt_pk_bf16(a.z, a.w);
    u.i4[2] = cvt_pk_bf16(c.x, c.y);
    u.i4[3] = cvt_pk_bf16(c.z, c.w);
    af[kc] = u.v;
  }
  const int Lb0 = tid * 16, Lb1 = 4096 + tid * 16;
  const int P0 = Lb0 ^ (((Lb0 >> 9) & 7) << 4);
  const int P1 = Lb1 ^ (((Lb1 >> 9) & 7) << 4);
  int rdo[8];
  #pragma unroll
  for (int kc = 0; kc < 8; ++kc) {
    int Lg = lr * 512 + kc * 64 + lg * 16;
    rdo[kc] = Lg ^ ((lr & 7) << 4);
  }
  {
    int4 s0 = *reinterpret_cast<const int4*>(Wb + Lb0);
    int4 s1 = *reinterpret_cast<const int4*>(Wb + Lb1);
    *reinterpret_cast<int4*>(lbase + P0) = s0;
    *reinterpret_cast<int4*>(lbase + P1) = s1;
  }
  __syncthreads();
  #pragma unroll 2
  for (int nt = 0; nt < 16; ++nt) {
    const int cur = nt & 1, nxt = cur ^ 1;
    int4 t0, t1;
    if (nt < 15) {
      t0 = *reinterpret_cast<const int4*>(Wb + (nt + 1) * 8192 + Lb0);
      t1 = *reinterpret_cast<const int4*>(Wb + (nt + 1) * 8192 + Lb1);
    }
    f32x4 acc = {0.f, 0.f, 0.f, 0.f};
    #pragma unroll
    for (int kc = 0; kc < 8; ++kc) {
      bf16x8 bfr = *reinterpret_cast<const bf16x8*>(lbase + cur * 8192 + rdo[kc]);
      acc = mfma_k32(af[kc], bfr, acc);
    }
    int colb = nt * 16 + lr;
    int h = colb >> 5, d = colb & 31;
    if (wi == 2) {
      int m = m0 + w * 16 + lg * 4;
      int b = m >> 10, n0 = m & 1023;
      int js = n0 >> 5;
      int lgv = (n0 & 15) >> 2, hi = (n0 >> 4) & 1;
      int jp = lgv * 8 + hi * 4;
      short4 vv;
      vv.x = f2bf(acc[0]); vv.y = f2bf(acc[1]);
      vv.z = f2bf(acc[2]); vv.w = f2bf(acc[3]);
      *reinterpret_cast<short4*>(
          &Vt[(((size_t)(b * 8 + h) * 32 + js) << 10) + d * 32 + jp]) = vv;
    } else {
      #pragma unroll
      for (int r = 0; r < 4; ++r) {
        int m = m0 + w * 16 + lg * 4 + r;
        int b = m >> 10, n = m & 1023;
        short val = (wi == 0) ? f2bf(acc[r] * CSQ) : f2bf(acc[r]);
        if (wi == 0)
          Q[((size_t)(b * 8 + h) * 1024 + n) * 32 + d] = val;
        else
          K[((size_t)(b * 8 + h) * 1024 + n) * 32 + d] = val;
      }
    }
    if (nt < 15) {
      *reinterpret_cast<int4*>(lbase + nxt * 8192 + P0) = t0;
      *reinterpret_cast<int4*>(lbase + nxt * 8192 + P1) = t1;
    }
    __syncthreads();
  }
}

// ------- kernel 2: flash attention, 8 waves, j-split, MFMA-ones row-sums -------
__global__ __launch_bounds__(512) void k_attn(const short* __restrict__ Q,
    const short* __restrict__ K, const short* __restrict__ Vt,
    const float* __restrict__ Tg, short* __restrict__ aout) {
  __shared__ char smraw[24576];
  float* Tlds = (float*)smraw;                       // 3969 f32 (bias table)
  auto mO  = (float(*)[4][4][64])smraw;              // [w][slot][r][l] 16KB
  auto mls = (float(*)[2][4][64])(smraw + 16384);    // [w][tile][r][l] 8KB
  const int tid = threadIdx.x, bid = blockIdx.x;
  const int h = bid & 7, qt = (bid >> 3) & 7, b = bid >> 6;
  const float* Th = Tg + (h << 12);
  for (int t = tid; t < 3969; t += 512) Tlds[t] = Th[t];
  __syncthreads();
  const int wg = tid >> 6, l = tid & 63, lr = l & 15, lg = l >> 4;
  const int w = wg & 3, jh = wg >> 2;
  const size_t hoff = (size_t)(b * 8 + h) << 15;
  const short* Qh = Q + hoff;
  const short* Kh = K + hoff;
  const short* Vh = Vt + hoff;
  const int ita = qt * 4 + w;          // 0..31
  const int i0a = ita * 16;            // rows 0..511
  const int i0b = i0a + 512;           // rows 512..1023 (same x-parity)
  const int yia = ita >> 1;
  const int pbase = ((ita & 1) << 4) + lr - lg * 4 + 31;
  bf16x8 qfa = *reinterpret_cast<const bf16x8*>(&Qh[(i0a + lr) * 32 + lg * 8]);
  bf16x8 qfb = *reinterpret_cast<const bf16x8*>(&Qh[(i0b + lr) * 32 + lg * 8]);
  bf16x8 ones;
  #pragma unroll
  for (int e = 0; e < 8; ++e) ones[e] = (short)0x3F80;  // bf16 1.0
  f32x4 oa0 = {0.f,0.f,0.f,0.f}, oa1 = {0.f,0.f,0.f,0.f};
  f32x4 ob0 = {0.f,0.f,0.f,0.f}, ob1 = {0.f,0.f,0.f,0.f};
  f32x4 lsa = {0.f,0.f,0.f,0.f}, lsb = {0.f,0.f,0.f,0.f};
  const int koff0 = lr * 32 + lg * 8, koff1 = (16 + lr) * 32 + lg * 8;
  const int js0 = jh * 16, jsE = js0 + 16;
  bf16x8 kf0 = *reinterpret_cast<const bf16x8*>(&Kh[(js0 << 10) + koff0]);
  bf16x8 kf1 = *reinterpret_cast<const bf16x8*>(&Kh[(js0 << 10) + koff1]);
  bf16x8 vf0 = *reinterpret_cast<const bf16x8*>(&Vh[(js0 << 10) + koff0]);
  bf16x8 vf1 = *reinterpret_cast<const bf16x8*>(&Vh[(js0 << 10) + koff1]);
  #pragma unroll 4
  for (int js = js0; js < jsE; ++js) {
    const int jn = (js + 1 < jsE) ? js + 1 : js;  // last iter: redundant reload
    bf16x8 nkf0 = *reinterpret_cast<const bf16x8*>(&Kh[(jn << 10) + koff0]);
    bf16x8 nkf1 = *reinterpret_cast<const bf16x8*>(&Kh[(jn << 10) + koff1]);
    bf16x8 nvf0 = *reinterpret_cast<const bf16x8*>(&Vh[(jn << 10) + koff0]);
    bf16x8 nvf1 = *reinterpret_cast<const bf16x8*>(&Vh[(jn << 10) + koff1]);
    const float* TrowA = &Tlds[(yia - js + 31) * 63];
    f32x4 bA0 = ldb(TrowA, pbase);
    f32x4 bA1 = ldb(TrowA, pbase - 16);
    f32x4 bB0 = ldb(TrowA + 1008, pbase);        // TrowB = TrowA + 16*63
    f32x4 bB1 = ldb(TrowA + 1008, pbase - 16);
    f32x4 sa0 = mfma_k32(kf0, qfa, bA0);  // score*CSQ + bias*l2e, row i0a+lr
    f32x4 sa1 = mfma_k32(kf1, qfa, bA1);
    f32x4 sb0 = mfma_k32(kf0, qfb, bB0);  // row i0b+lr
    f32x4 sb1 = mfma_k32(kf1, qfb, bB1);
    float pa0[4], pa1[4], pb0[4], pb1[4];
    #pragma unroll
    for (int r = 0; r < 4; ++r) {
      pa0[r] = __builtin_amdgcn_exp2f(sa0[r]);
      pa1[r] = __builtin_amdgcn_exp2f(sa1[r]);
      pb0[r] = __builtin_amdgcn_exp2f(sb0[r]);
      pb1[r] = __builtin_amdgcn_exp2f(sb1[r]);
    }
    union { int i4[4]; bf16x8 v; } pka, pkb;
    pka.i4[0] = cvt_pk_bf16(pa0[0], pa0[1]);
    pka.i4[1] = cvt_pk_bf16(pa0[2], pa0[3]);
    pka.i4[2] = cvt_pk_bf16(pa1[0], pa1[1]);
    pka.i4[3] = cvt_pk_bf16(pa1[2], pa1[3]);
    pkb.i4[0] = cvt_pk_bf16(pb0[0], pb0[1]);
    pkb.i4[1] = cvt_pk_bf16(pb0[2], pb0[3]);
    pkb.i4[2] = cvt_pk_bf16(pb1[0], pb1[1]);
    pkb.i4[3] = cvt_pk_bf16(pb1[2], pb1[3]);
    oa0 = mfma_k32(pka.v, vf0, oa0);   // O[i0a+lg*4+r][d=lr]
    oa1 = mfma_k32(pka.v, vf1, oa1);   // O[i0a+..][d=16+lr]
    lsa = mfma_k32(pka.v, ones, lsa);  // rowsum(i0a+lg*4+r), all lr
    ob0 = mfma_k32(pkb.v, vf0, ob0);
    ob1 = mfma_k32(pkb.v, vf1, ob1);
    lsb = mfma_k32(pkb.v, ones, lsb);
    kf0 = nkf0; kf1 = nkf1; vf0 = nvf0; vf1 = nvf1;
  }
  // all waves done with Tlds before merge buffers overwrite it
  __syncthreads();
  if (jh == 1) {
    #pragma unroll
    for (int r = 0; r < 4; ++r) {
      mO[w][0][r][l] = oa0[r];
      mO[w][1][r][l] = oa1[r];
      mO[w][2][r][l] = ob0[r];
      mO[w][3][r][l] = ob1[r];
      mls[w][0][r][l] = lsa[r];
      mls[w][1][r][l] = lsb[r];
    }
  }
  __syncthreads();
  if (jh == 0) {
    #pragma unroll
    for (int r = 0; r < 4; ++r) {
      oa0[r] += mO[w][0][r][l];
      oa1[r] += mO[w][1][r][l];
      ob0[r] += mO[w][2][r][l];
      ob1[r] += mO[w][3][r][l];
      lsa[r] += mls[w][0][r][l];
      lsb[r] += mls[w][1][r][l];
    }
    #pragma unroll
    for (int r = 0; r < 4; ++r) {
      float invr = 1.0f / lsa[r];  // rowsum(i0a+lg*4+r) -- already per-lane
      int n = i0a + lg * 4 + r;
      size_t base = ((size_t)b << 18) + (size_t)n * 256 + h * 32;
      aout[base + lr]      = f2bf(oa0[r] * invr);
      aout[base + 16 + lr] = f2bf(oa1[r] * invr);
    }
    #pragma unroll
    for (int r = 0; r < 4; ++r) {
      float invr = 1.0f / lsb[r];
      int n = i0b + lg * 4 + r;
      size_t base = ((size_t)b << 18) + (size_t)n * 256 + h * 32;
      aout[base + lr]      = f2bf(ob0[r] * invr);
      aout[base + 16 + lr] = f2bf(ob1[r] * invr);
    }
  }
}

// ------- kernel 3: output projection, W via dbuf LDS, 2-way nt split ----------
__global__ __launch_bounds__(256) void k_outproj(const short* __restrict__ aout,
    const short* __restrict__ WoT, const float* __restrict__ bo,
    float* __restrict__ out) {
  __shared__ short Wlds[2][4096];
  char* lbase = (char*)Wlds;
  const int tid = threadIdx.x;
  const int w = tid >> 6, l = tid & 63, lr = l & 15, lg = l >> 4;
  const int m0 = blockIdx.x * 64;
  const int nt0 = blockIdx.y * 8;
  const char* Wb = (const char*)WoT + nt0 * 8192;
  const short* arow = aout + (size_t)(m0 + w * 16 + lr) * 256;
  bf16x8 af[8];
  #pragma unroll
  for (int kc = 0; kc < 8; ++kc)
    af[kc] = *reinterpret_cast<const bf16x8*>(arow + kc * 32 + lg * 8);
  const int Lb0 = tid * 16, Lb1 = 4096 + tid * 16;
  const int P0 = Lb0 ^ (((Lb0 >> 9) & 7) << 4);
  const int P1 = Lb1 ^ (((Lb1 >> 9) & 7) << 4);
  int rdo[8];
  #pragma unroll
  for (int kc = 0; kc < 8; ++kc) {
    int Lg = lr * 512 + kc * 64 + lg * 16;
    rdo[kc] = Lg ^ ((lr & 7) << 4);
  }
  {
    int4 s0 = *reinterpret_cast<const int4*>(Wb + Lb0);
    int4 s1 = *reinterpret_cast<const int4*>(Wb + Lb1);
    *reinterpret_cast<int4*>(lbase + P0) = s0;
    *reinterpret_cast<int4*>(lbase + P1) = s1;
  }
  __syncthreads();
  #pragma unroll 2
  for (int t = 0; t < 8; ++t) {
    const int cur = t & 1, nxt = cur ^ 1;
    int4 t0, t1;
    if (t < 7) {
      t0 = *reinterpret_cast<const int4*>(Wb + (t + 1) * 8192 + Lb0);
      t1 = *reinterpret_cast<const int4*>(Wb + (t + 1) * 8192 + Lb1);
    }
    f32x4 acc = {0.f, 0.f, 0.f, 0.f};
    #pragma unroll
    for (int kc = 0; kc < 8; ++kc) {
      bf16x8 bfr = *reinterpret_cast<const bf16x8*>(lbase + cur * 8192 + rdo[kc]);
      acc = mfma_k32(af[kc], bfr, acc);
    }
    int colb = (nt0 + t) * 16 + lr;
    float bias = bo[colb];
    #pragma unroll
    for (int r = 0; r < 4; ++r) {
      int m = m0 + w * 16 + lg * 4 + r;
      out[(size_t)m * 256 + colb] = acc[r] + bias;
    }
    if (t < 7) {
      *reinterpret_cast<int4*>(lbase + nxt * 8192 + P0) = t0;
      *reinterpret_cast<int4*>(lbase + nxt * 8192 + P1) = t1;
    }
    __syncthreads();
  }
}

extern "C" void kernel_launch(void* const* d_in, const int* in_sizes, int n_in,
                              void* d_out, int out_size, void* d_ws, size_t ws_size,
                              hipStream_t stream) {
  const float* x  = (const float*)d_in[0];
  const float* Wq = (const float*)d_in[1];
  const float* Wk = (const float*)d_in[2];
  const float* Wv = (const float*)d_in[3];
  const float* bt = (const float*)d_in[4];
  const float* Wo = (const float*)d_in[5];
  const float* bo = (const float*)d_in[6];
  float* out = (float*)d_out;
  char* ws = (char*)d_ws;
  short* WT   = (short*)ws;                          // 4 x 65536 shorts = 512 KB
  short* Qs   = (short*)(ws + 512 * 1024);           // 8 MB each
  short* Ks   = Qs + 4194304;
  short* Vts  = Ks + 4194304;
  short* aout = Vts + 4194304;
  float* Tg   = (float*)(ws + 512 * 1024 + 4ull * 8388608);  // 8x4096 f32 = 128 KB

  k_prep<<<192, 256, 0, stream>>>(Wq, Wk, Wv, Wo, WT, bt, Tg);
  k_qkv<<<dim3(256, 3), 256, 0, stream>>>(x, WT, Qs, Ks, Vts);
  k_attn<<<1024, 512, 0, stream>>>(Qs, Ks, Vts, Tg, aout);
  k_outproj<<<dim3(256, 2), 256, 0, stream>>>(aout, WT + 3 * 65536, bo, out);
}